// Round 5
// baseline (61.057 us; speedup 1.0000x reference)
//
#include <hip/hip_runtime.h>

// Problem constants (from reference):
//   codes:     [4096, 1376, 2] int32  (45 MB, read-once)
//   codebooks: [2, 256, 1, 8]  float32 (16 KB total, hot)
//   scales:    [4096, 1, 1, 1] float32
//   out:       [4096, 11008]   float32 (180.4 MB, write-once)
#define NOG 4096
#define NIG 1376
#define PAIRS_PER_THREAD 8
#define BLOCK 256
// total pairs = 4096*1376 = 5,636,096 = 2752 blocks * 256 threads * 8 iters
#define NBLOCKS 2752
#define ITER_STRIDE (NBLOCKS * BLOCK)   // 704,512 pairs per grid-iteration

// Native clang vector types — required by __builtin_nontemporal_{load,store}
typedef float fx4 __attribute__((ext_vector_type(4)));
typedef int   ix2 __attribute__((ext_vector_type(2)));

__global__ __launch_bounds__(BLOCK)
void aqlm_dequant_kernel(const ix2* __restrict__ codes,      // [NOG*NIG]
                         const fx4* __restrict__ codebooks,  // 1024 fx4 (16 KB)
                         const float* __restrict__ scales,   // [NOG]
                         fx4* __restrict__ out)               // [NOG*NIG*2]
{
    // Stage both codebooks in LDS once per block; amortized over 8 pairs/thread.
    // book0 entry e -> lds_cb[2e, 2e+1]; book1 entry e -> lds_cb[512+2e, 512+2e+1]
    __shared__ fx4 lds_cb[1024];
    const int tid = threadIdx.x;
#pragma unroll
    for (int i = 0; i < 4; ++i)
        lds_cb[tid + i * BLOCK] = codebooks[tid + i * BLOCK];
    __syncthreads();

    const int base = blockIdx.x * BLOCK + tid;

#pragma unroll
    for (int it = 0; it < PAIRS_PER_THREAD; ++it) {
        const int gid = base + it * ITER_STRIDE;    // coalesced within each iter
        const int og  = gid / NIG;                  // magic-mul, cheap

        const ix2 c  = __builtin_nontemporal_load(&codes[gid]);
        const float s = scales[og];

        const fx4 a0 = lds_cb[c.x * 2];
        const fx4 a1 = lds_cb[c.x * 2 + 1];
        const fx4 b0 = lds_cb[512 + c.y * 2];
        const fx4 b1 = lds_cb[512 + c.y * 2 + 1];

        const fx4 w0 = (a0 + b0) * s;
        const fx4 w1 = (a1 + b1) * s;

        __builtin_nontemporal_store(w0, &out[gid * 2]);      // 2 KB/wave contiguous
        __builtin_nontemporal_store(w1, &out[gid * 2 + 1]);
    }
}

extern "C" void kernel_launch(void* const* d_in, const int* in_sizes, int n_in,
                              void* d_out, int out_size, void* d_ws, size_t ws_size,
                              hipStream_t stream) {
    const ix2*   codes     = (const ix2*)d_in[0];
    const fx4*   codebooks = (const fx4*)d_in[1];
    const float* scales    = (const float*)d_in[2];
    fx4*         out       = (fx4*)d_out;

    aqlm_dequant_kernel<<<NBLOCKS, BLOCK, 0, stream>>>(codes, codebooks, scales, out);
}

// Round 6
// 40.048 us; speedup vs baseline: 1.5246x; 1.5246x over previous
//
#include <hip/hip_runtime.h>

// Problem constants (from reference):
//   codes:     [4096, 1376, 2] int32  (45 MB, read-once)
//   codebooks: [2, 256, 1, 8]  float32 (16 KB total, hot)
//   scales:    [4096, 1, 1, 1] float32
//   out:       [4096, 11008]   float32 (180.4 MB, write-once)
#define NOG 4096
#define NIG 1376
#define PAIRS_PER_THREAD 8
#define BLOCK 256
// total pairs = 4096*1376 = 5,636,096 = 2752 blocks * 256 threads * 8 iters
#define NBLOCKS 2752
#define ITER_STRIDE (NBLOCKS * BLOCK)   // 704,512 pairs per grid-iteration

// Native clang vector types (convenient arithmetic, same codegen as HIP types)
typedef float fx4 __attribute__((ext_vector_type(4)));
typedef int   ix2 __attribute__((ext_vector_type(2)));

__global__ __launch_bounds__(BLOCK)
void aqlm_dequant_kernel(const ix2* __restrict__ codes,      // [NOG*NIG]
                         const fx4* __restrict__ codebooks,  // 1024 fx4 (16 KB)
                         const float* __restrict__ scales,   // [NOG]
                         fx4* __restrict__ out)               // [NOG*NIG*2]
{
    // Stage both codebooks in LDS once per block; amortized over 8 pairs/thread.
    // book0 entry e -> lds_cb[2e, 2e+1]; book1 entry e -> lds_cb[512+2e, 512+2e+1]
    __shared__ fx4 lds_cb[1024];
    const int tid = threadIdx.x;
#pragma unroll
    for (int i = 0; i < 4; ++i)
        lds_cb[tid + i * BLOCK] = codebooks[tid + i * BLOCK];
    __syncthreads();

    const int base = blockIdx.x * BLOCK + tid;

#pragma unroll
    for (int it = 0; it < PAIRS_PER_THREAD; ++it) {
        const int gid = base + it * ITER_STRIDE;    // coalesced within each iter
        const int og  = gid / NIG;                  // magic-mul, cheap

        const ix2 c  = codes[gid];                  // plain load (A/B vs round 4)
        const float s = scales[og];

        const fx4 a0 = lds_cb[c.x * 2];
        const fx4 a1 = lds_cb[c.x * 2 + 1];
        const fx4 b0 = lds_cb[512 + c.y * 2];
        const fx4 b1 = lds_cb[512 + c.y * 2 + 1];

        const fx4 w0 = (a0 + b0) * s;
        const fx4 w1 = (a1 + b1) * s;

        out[gid * 2]     = w0;    // plain stores: let L2 merge the half-dense
        out[gid * 2 + 1] = w1;    // 32B-stride pattern into full lines
    }
}

extern "C" void kernel_launch(void* const* d_in, const int* in_sizes, int n_in,
                              void* d_out, int out_size, void* d_ws, size_t ws_size,
                              hipStream_t stream) {
    const ix2*   codes     = (const ix2*)d_in[0];
    const fx4*   codebooks = (const fx4*)d_in[1];
    const float* scales    = (const float*)d_in[2];
    fx4*         out       = (fx4*)d_out;

    aqlm_dequant_kernel<<<NBLOCKS, BLOCK, 0, stream>>>(codes, codebooks, scales, out);
}

// Round 7
// 38.165 us; speedup vs baseline: 1.5998x; 1.0494x over previous
//
#include <hip/hip_runtime.h>

// Problem constants (from reference):
//   codes:     [4096, 1376, 2] int32  (45 MB, read-once)
//   codebooks: [2, 256, 1, 8]  float32 (16 KB total, hot)
//   scales:    [4096, 1, 1, 1] float32
//   out:       [4096, 11008]   float32 (180.4 MB, write-once)
//
// This version: ONE float4 output per thread-iter (dense wave stores).
//   f = flat float4 index into out; pair = f>>1 selects codes; half = f&1
//   selects which half of the two 8-float codebook entries.
#define NOG 4096
#define NIG 1376
#define BLOCK 256
#define NBLOCKS 2752
#define ITERS 16
// float4 outputs total = 4096*11008/4 = 11,272,192 = 2752*256*16 exactly
#define ITER_STRIDE (NBLOCKS * BLOCK)   // 704,512 float4 per grid-iteration

typedef float fx4 __attribute__((ext_vector_type(4)));
typedef int   ix2 __attribute__((ext_vector_type(2)));

__global__ __launch_bounds__(BLOCK)
void aqlm_dequant_kernel(const ix2* __restrict__ codes,      // [NOG*NIG]
                         const fx4* __restrict__ codebooks,  // 1024 fx4 (16 KB)
                         const float* __restrict__ scales,   // [NOG]
                         fx4* __restrict__ out)               // [NOG*NIG*2]
{
    // Stage both codebooks in LDS once per block; amortized over 16 f4/thread.
    // book0 entry e -> lds_cb[2e, 2e+1]; book1 entry e -> lds_cb[512+2e, 512+2e+1]
    __shared__ fx4 lds_cb[1024];
    const int tid = threadIdx.x;
#pragma unroll
    for (int i = 0; i < 4; ++i)
        lds_cb[tid + i * BLOCK] = codebooks[tid + i * BLOCK];
    __syncthreads();

    const int base = blockIdx.x * BLOCK + tid;

#pragma unroll
    for (int it = 0; it < ITERS; ++it) {
        const int f    = base + it * ITER_STRIDE;   // dense float4 index
        const int pair = f >> 1;                    // (og, ig) pair index
        const int half = f & 1;                     // which 16B half of the 32B group
        const int og   = pair / NIG;                // magic-mul

        const ix2 c  = codes[pair];                 // even/odd lanes share an int2
        const float s = scales[og];

        const fx4 a = lds_cb[c.x * 2 + half];
        const fx4 b = lds_cb[512 + c.y * 2 + half];

        out[f] = (a + b) * s;   // wave store = contiguous, aligned 1 KB span
    }
}

extern "C" void kernel_launch(void* const* d_in, const int* in_sizes, int n_in,
                              void* d_out, int out_size, void* d_ws, size_t ws_size,
                              hipStream_t stream) {
    const ix2*   codes     = (const ix2*)d_in[0];
    const fx4*   codebooks = (const fx4*)d_in[1];
    const float* scales    = (const float*)d_in[2];
    fx4*         out       = (fx4*)d_out;

    aqlm_dequant_kernel<<<NBLOCKS, BLOCK, 0, stream>>>(codes, codebooks, scales, out);
}